// Round 25
// baseline (99.197 us; speedup 1.0000x reference)
//
#include <hip/hip_runtime.h>
#include <hip/hip_fp8.h>

#define NN 50000
#define DIM 64
#define NE 1250000
#define NPARTS 196  // ceil(50000/256)

// ---- counting-sort CSR build: 64 edge-slices x 8 row-ranges = 512 blocks
#define NSL 64
#define SLICEB 19532          // ceil(NE / NSL); 19532*64 = 1250048 >= NE
#define RANGE 6250            // NN / 8 rows per range
#define CSTRIDE 50048         // padded row stride of cnt matrix

typedef __attribute__((ext_vector_type(2))) float f32x2;

// bf16 helpers (RNE pack, cheap unpack)
__device__ __forceinline__ unsigned short f2b(float f) {
    unsigned int b = __builtin_bit_cast(unsigned int, f);
    b = (b + 0x7fffu + ((b >> 16) & 1u)) >> 16;
    return (unsigned short)b;
}
__device__ __forceinline__ float blo(unsigned int u) {
    return __builtin_bit_cast(float, u << 16);
}
__device__ __forceinline__ float bhi(unsigned int u) {
    return __builtin_bit_cast(float, u & 0xffff0000u);
}

// fp8 e4m3 (OCP) helpers — hardware cvt on gfx950; word-select must be constant.
template <bool HI>
__device__ __forceinline__ f32x2 dec2(unsigned int u) {
#if __has_builtin(__builtin_amdgcn_cvt_pk_f32_fp8)
    return __builtin_amdgcn_cvt_pk_f32_fp8(u, HI);
#else
    unsigned int b0 = HI ? ((u >> 16) & 0xff) : (u & 0xff);
    unsigned int b1 = HI ? ((u >> 24) & 0xff) : ((u >> 8) & 0xff);
    __hip_fp8_e4m3 t0, t1;
    t0.__x = (unsigned char)b0;
    t1.__x = (unsigned char)b1;
    f32x2 r;
    r[0] = (float)t0;
    r[1] = (float)t1;
    return r;
#endif
}
__device__ __forceinline__ unsigned int enc4(float v0, float v1, float v2, float v3) {
#if __has_builtin(__builtin_amdgcn_cvt_pk_fp8_f32)
    unsigned int r = 0;
    r = __builtin_amdgcn_cvt_pk_fp8_f32(v0, v1, r, false);
    r = __builtin_amdgcn_cvt_pk_fp8_f32(v2, v3, r, true);
    return r;
#else
    __hip_fp8_e4m3 t0(v0), t1(v1), t2(v2), t3(v3);
    return (unsigned int)t0.__x | ((unsigned int)t1.__x << 8) |
           ((unsigned int)t2.__x << 16) | ((unsigned int)t3.__x << 24);
#endif
}

// ---------------- hist + bucket staging + fp8 cvt side-job ----------------
// bid -> slice s = (bid&7)|((bid>>6)<<3), rng = (bid>>3)&7 (bid%8 == s%8:
// same-slice blocks co-scheduled on one XCD -> slice read into L2 once).
// Stages each in-range edge as packed (r-lo)<<16 | col into bucket
// (s*8+rng)*SLICEB via wave-aggregated ballot append (one LDS atomic/wave).
__global__ __launch_bounds__(1024) void k_hist(const int* __restrict__ row,
                                               const int* __restrict__ col,
                                               const float* __restrict__ emb,
                                               unsigned char* __restrict__ x08,
                                               unsigned short* __restrict__ cnt,
                                               unsigned int* __restrict__ stage,
                                               int* __restrict__ bsize) {
    __shared__ int h[RANGE];
    __shared__ int bcnt;
    int bid = blockIdx.x;
    int s   = (bid & 7) | ((bid >> 6) << 3);
    int rng = (bid >> 3) & 7;
    int lo = rng * RANGE;
    int tid = threadIdx.x;
    for (int i = tid; i < RANGE; i += 1024) h[i] = 0;
    if (tid == 0) bcnt = 0;
    __syncthreads();
    int beg = s * SLICEB;
    int end = beg + SLICEB;
    if (end > NE) end = NE;
    unsigned int* st = stage + (size_t)(s * 8 + rng) * SLICEB;
    int lane = tid & 63;
    for (int e = beg + tid; e < end; e += 1024) {
        int r = row[e] - lo;
        bool ok = (unsigned)r < RANGE;
        unsigned long long mask = __ballot(ok);
        if (ok) {
            int leader = __ffsll((long long)mask) - 1;
            int base = 0;
            if (lane == leader) base = atomicAdd(&bcnt, __popcll(mask));
            base = __shfl(base, leader);
            int off = __popcll(mask & ((1ull << lane) - 1ull));
            st[base + off] = ((unsigned int)r << 16) | (unsigned int)col[e];
            atomicAdd(&h[r], 1);  // LDS atomic
        }
    }
    __syncthreads();
    unsigned short* c = cnt + s * CSTRIDE + lo;
    for (int i = tid; i < RANGE; i += 1024) c[i] = (unsigned short)h[i];
    if (tid == 0) bsize[s * 8 + rng] = bcnt;
    // ----- independent side-job: fp32 emb -> fp8 mirror (1 iter/thread) -----
    for (int t = bid * 1024 + tid; t < NN * DIM / 8; t += 512 * 1024) {
        const float4* p = (const float4*)emb + t * 2;
        float4 a = p[0], b = p[1];
        uint2 pk;
        pk.x = enc4(a.x, a.y, a.z, a.w);
        pk.y = enc4(b.x, b.y, b.z, b.w);
        ((uint2*)x08)[t] = pk;
    }
}

// ---------------- rowscan + partial-sum fusion ----------------
__global__ __launch_bounds__(256) void k_rowscan(unsigned short* __restrict__ cnt,
                                                 int* __restrict__ deg,
                                                 int* __restrict__ partial) {
    __shared__ int sred[256];
    int t = threadIdx.x;
    int r = blockIdx.x * 256 + t;
    int acc = 0;
    if (r < NN) {
#pragma unroll
        for (int s = 0; s < NSL; ++s) {
            int c = cnt[s * CSTRIDE + r];
            cnt[s * CSTRIDE + r] = (unsigned short)acc;  // exclusive within-row offset
            acc += c;
        }
        deg[r] = acc;
    }
    sred[t] = acc;
    __syncthreads();
    for (int off = 128; off > 0; off >>= 1) {
        if (t < off) sred[t] += sred[t + off];
        __syncthreads();
    }
    if (t == 0) partial[blockIdx.x] = sred[0];
}

// ---------------- scan_final with inline top-scan ----------------
__global__ __launch_bounds__(256) void k_scan_final(const int* __restrict__ deg,
                                                    const int* __restrict__ partial,
                                                    int* __restrict__ offs) {
    __shared__ int ps[256];
    __shared__ int s[256];
    int t = threadIdx.x;
    ps[t] = (t < NPARTS) ? partial[t] : 0;
    __syncthreads();
    for (int off = 1; off < 256; off <<= 1) {
        int x = (t >= off) ? ps[t - off] : 0;
        __syncthreads();
        ps[t] += x;
        __syncthreads();
    }
    int bpre = (blockIdx.x == 0) ? 0 : ps[blockIdx.x - 1];
    int i = blockIdx.x * 256 + t;
    int v = (i < NN) ? deg[i] : 0;
    s[t] = v;
    __syncthreads();
    for (int off = 1; off < 256; off <<= 1) {
        int x = (t >= off) ? s[t - off] : 0;
        __syncthreads();
        s[t] += x;
        __syncthreads();
    }
    int excl = s[t] - v;
    if (i <= NN) offs[i] = bpre + excl;  // offs[NN] = NE (total)
}

// ---------------- CSR fill from staged buckets (NO global atomics) ----------------
__global__ __launch_bounds__(1024) void k_fillb(const unsigned int* __restrict__ stage,
                                                const int* __restrict__ bsize,
                                                const int* __restrict__ offs,
                                                const unsigned short* __restrict__ cnt,
                                                int* __restrict__ csr) {
    __shared__ int cur[RANGE];
    int bid = blockIdx.x;
    int s   = bid >> 3;
    int rng = bid & 7;
    int lo = rng * RANGE;
    int tid = threadIdx.x;
    const unsigned short* c = cnt + s * CSTRIDE + lo;
    const int* o = offs + lo;
    for (int i = tid; i < RANGE; i += 1024) cur[i] = o[i] + c[i];
    __syncthreads();
    int nb = bsize[s * 8 + rng];
    const unsigned int* st = stage + (size_t)(s * 8 + rng) * SLICEB;
    for (int i = tid; i < nb; i += 1024) {
        unsigned int pk = st[i];
        int r = pk >> 16;
        int pos = atomicAdd(&cur[r], 1);  // LDS atomic
        csr[pos] = (int)(pk & 0xffffu);
    }
}

// ---------------- one propagation layer (fp8 gather, fp32 accum) ----------------
// 16 nodes per wave: lane>>2 = node in wave (0..15), lane&3 = feature-16-group.
// Each lane loads uint4 (16 fp8, 16 B) -> one vector-mem instruction fetches
// 16 rows (1 KB); gather instruction count halves vs the 8-node version.
// DISCRIMINATING EXPERIMENT: if layers are issue-bound this wins ~3 us/layer;
// if line-transaction-bound (1.25M lines/layer compulsory) it's null.
// Accumulation order per feature unchanged (one lane owns each feature,
// same even/odd-edge a/b banks) -> absmax should stay 0.01171875.
#define DEC16(U, A0,A1,A2,A3,A4,A5,A6,A7,A8,A9,A10,A11,A12,A13,A14,A15) { \
    f32x2 p;                                                              \
    p = dec2<false>(U.x); A0 += p[0];  A1 += p[1];                        \
    p = dec2<true >(U.x); A2 += p[0];  A3 += p[1];                        \
    p = dec2<false>(U.y); A4 += p[0];  A5 += p[1];                        \
    p = dec2<true >(U.y); A6 += p[0];  A7 += p[1];                        \
    p = dec2<false>(U.z); A8 += p[0];  A9 += p[1];                        \
    p = dec2<true >(U.z); A10 += p[0]; A11 += p[1];                       \
    p = dec2<false>(U.w); A12 += p[0]; A13 += p[1];                       \
    p = dec2<true >(U.w); A14 += p[0]; A15 += p[1]; }
#define DECA(U) DEC16(U, a0,a1,a2,a3,a4,a5,a6,a7,a8,a9,a10,a11,a12,a13,a14,a15)
#define DECB(U) DEC16(U, b0,b1,b2,b3,b4,b5,b6,b7,b8,b9,b10,b11,b12,b13,b14,b15)

template <int PHASE>
__global__ __launch_bounds__(256) void k_layer(const unsigned char* __restrict__ xin8,
                                               const float* __restrict__ emb,
                                               const unsigned short* __restrict__ xa16,
                                               const unsigned short* __restrict__ xb16,
                                               unsigned short* __restrict__ xout16,
                                               unsigned char* __restrict__ xout8,
                                               float* __restrict__ out,
                                               const int* __restrict__ offs,
                                               const int* __restrict__ csr) {
    int wid = (blockIdx.x * blockDim.x + threadIdx.x) >> 6;
    int lane = threadIdx.x & 63;
    int sub = lane >> 2;    // node within wave (0..15)
    int sl = lane & 3;      // feature-16-group (0..3)
    int n = 16 * wid + sub;
    if (n >= NN) return;
    int beg = offs[n];
    int end = offs[n + 1];
    const unsigned char* xq = xin8 + sl * 16;  // + c*64 bytes per neighbor

    float a0 = 0.f, a1 = 0.f, a2 = 0.f, a3 = 0.f, a4 = 0.f, a5 = 0.f, a6 = 0.f, a7 = 0.f;
    float a8 = 0.f, a9 = 0.f, a10 = 0.f, a11 = 0.f, a12 = 0.f, a13 = 0.f, a14 = 0.f, a15 = 0.f;
    float b0 = 0.f, b1 = 0.f, b2 = 0.f, b3 = 0.f, b4 = 0.f, b5 = 0.f, b6 = 0.f, b7 = 0.f;
    float b8 = 0.f, b9 = 0.f, b10 = 0.f, b11 = 0.f, b12 = 0.f, b13 = 0.f, b14 = 0.f, b15 = 0.f;
    int e = beg;
    for (; e + 8 <= end; e += 8) {
        int c0 = csr[e + 0], c1 = csr[e + 1], c2 = csr[e + 2], c3 = csr[e + 3];
        int c4 = csr[e + 4], c5 = csr[e + 5], c6 = csr[e + 6], c7 = csr[e + 7];
        uint4 u0 = *(const uint4*)(xq + c0 * 64);
        uint4 u1 = *(const uint4*)(xq + c1 * 64);
        uint4 u2 = *(const uint4*)(xq + c2 * 64);
        uint4 u3 = *(const uint4*)(xq + c3 * 64);
        uint4 u4 = *(const uint4*)(xq + c4 * 64);
        uint4 u5 = *(const uint4*)(xq + c5 * 64);
        uint4 u6 = *(const uint4*)(xq + c6 * 64);
        uint4 u7 = *(const uint4*)(xq + c7 * 64);
        DECA(u0); DECB(u1); DECA(u2); DECB(u3);
        DECA(u4); DECB(u5); DECA(u6); DECB(u7);
    }
    for (; e < end; ++e) {
        uint4 u = *(const uint4*)(xq + csr[e] * 64);
        DECA(u);
    }

    int d = end - beg;
    float inv = (d > 0) ? 1.0f / (float)d : 0.0f;
    float v0 = (a0 + b0) * inv,  v1 = (a1 + b1) * inv;
    float v2 = (a2 + b2) * inv,  v3 = (a3 + b3) * inv;
    float v4 = (a4 + b4) * inv,  v5 = (a5 + b5) * inv;
    float v6 = (a6 + b6) * inv,  v7 = (a7 + b7) * inv;
    float v8 = (a8 + b8) * inv,  v9 = (a9 + b9) * inv;
    float v10 = (a10 + b10) * inv, v11 = (a11 + b11) * inv;
    float v12 = (a12 + b12) * inv, v13 = (a13 + b13) * inv;
    float v14 = (a14 + b14) * inv, v15 = (a15 + b15) * inv;

    int o = n * DIM + sl * 16;
    if (PHASE < 2) {
        uint4 lo16 = {(unsigned int)f2b(v0) | ((unsigned int)f2b(v1) << 16),
                      (unsigned int)f2b(v2) | ((unsigned int)f2b(v3) << 16),
                      (unsigned int)f2b(v4) | ((unsigned int)f2b(v5) << 16),
                      (unsigned int)f2b(v6) | ((unsigned int)f2b(v7) << 16)};
        uint4 hi16 = {(unsigned int)f2b(v8) | ((unsigned int)f2b(v9) << 16),
                      (unsigned int)f2b(v10) | ((unsigned int)f2b(v11) << 16),
                      (unsigned int)f2b(v12) | ((unsigned int)f2b(v13) << 16),
                      (unsigned int)f2b(v14) | ((unsigned int)f2b(v15) << 16)};
        *(uint4*)(xout16 + o) = lo16;
        *(uint4*)(xout16 + o + 8) = hi16;
        uint4 pk8 = {enc4(v0, v1, v2, v3), enc4(v4, v5, v6, v7),
                     enc4(v8, v9, v10, v11), enc4(v12, v13, v14, v15)};
        *(uint4*)(xout8 + o) = pk8;
    } else {
        float4 e0 = *(const float4*)(emb + o);
        float4 e1 = *(const float4*)(emb + o + 4);
        float4 e2 = *(const float4*)(emb + o + 8);
        float4 e3 = *(const float4*)(emb + o + 12);
        uint4 ua0 = *(const uint4*)(xa16 + o);
        uint4 ua1 = *(const uint4*)(xa16 + o + 8);
        uint4 ub0 = *(const uint4*)(xb16 + o);
        uint4 ub1 = *(const uint4*)(xb16 + o + 8);
        float4 o0, o1, o2, o3;
        o0.x = 0.25f * (e0.x + blo(ua0.x) + blo(ub0.x) + v0);
        o0.y = 0.25f * (e0.y + bhi(ua0.x) + bhi(ub0.x) + v1);
        o0.z = 0.25f * (e0.z + blo(ua0.y) + blo(ub0.y) + v2);
        o0.w = 0.25f * (e0.w + bhi(ua0.y) + bhi(ub0.y) + v3);
        o1.x = 0.25f * (e1.x + blo(ua0.z) + blo(ub0.z) + v4);
        o1.y = 0.25f * (e1.y + bhi(ua0.z) + bhi(ub0.z) + v5);
        o1.z = 0.25f * (e1.z + blo(ua0.w) + blo(ub0.w) + v6);
        o1.w = 0.25f * (e1.w + bhi(ua0.w) + bhi(ub0.w) + v7);
        o2.x = 0.25f * (e2.x + blo(ua1.x) + blo(ub1.x) + v8);
        o2.y = 0.25f * (e2.y + bhi(ua1.x) + bhi(ub1.x) + v9);
        o2.z = 0.25f * (e2.z + blo(ua1.y) + blo(ub1.y) + v10);
        o2.w = 0.25f * (e2.w + bhi(ua1.y) + bhi(ub1.y) + v11);
        o3.x = 0.25f * (e3.x + blo(ua1.z) + blo(ub1.z) + v12);
        o3.y = 0.25f * (e3.y + bhi(ua1.z) + bhi(ub1.z) + v13);
        o3.z = 0.25f * (e3.z + blo(ua1.w) + blo(ub1.w) + v14);
        o3.w = 0.25f * (e3.w + bhi(ua1.w) + bhi(ub1.w) + v15);
        *(float4*)(out + o) = o0;
        *(float4*)(out + o + 4) = o1;
        *(float4*)(out + o + 8) = o2;
        *(float4*)(out + o + 12) = o3;
    }
}

extern "C" void kernel_launch(void* const* d_in, const int* in_sizes, int n_in,
                              void* d_out, int out_size, void* d_ws, size_t ws_size,
                              hipStream_t stream) {
    const int* edge = (const int*)d_in[0];
    const int* row = edge;        // edge_index[0]
    const int* col = edge + NE;   // edge_index[1]
    const float* emb = (const float*)d_in[1];
    float* out = (float*)d_out;

    // workspace layout (~75 MB of 256 MB)
    int* deg    = (int*)d_ws;                                // 50048 ints
    int* offs   = deg + 50048;                               // 50112 ints
    int* partial= offs + 50112;                              // 256 ints
    int* bsize  = partial + 256;                             // 512 ints (pad 576)
    int* csr    = bsize + 576;                               // 1250048 ints
    unsigned short* cnt = (unsigned short*)(csr + 1250048);  // 64*50048 ushort (6.4MB)
    unsigned short* xa16 = cnt + (size_t)NSL * CSTRIDE;      // 3.2M ushort
    unsigned short* xb16 = xa16 + NN * DIM;                  // 3.2M ushort
    unsigned char* x08 = (unsigned char*)(xb16 + NN * DIM);  // 3.2M bytes
    unsigned char* xa8 = x08 + NN * DIM;                     // 3.2M bytes
    unsigned char* xb8 = xa8 + NN * DIM;                     // 3.2M bytes
    unsigned int* stage = (unsigned int*)(xb8 + NN * DIM);   // 512*19532 uints (40MB)

    k_hist      <<<NSL * 8, 1024, 0, stream>>>(row, col, emb, x08, cnt, stage, bsize);
    k_rowscan   <<<NPARTS, 256, 0, stream>>>(cnt, deg, partial);
    k_scan_final<<<NPARTS, 256, 0, stream>>>(deg, partial, offs);
    k_fillb     <<<NSL * 8, 1024, 0, stream>>>(stage, bsize, offs, cnt, csr);

    // 16 nodes per wave: 3125 waves -> 782 blocks of 256 (guard in-kernel)
    int layer_blocks = 782;
    k_layer<0><<<layer_blocks, 256, 0, stream>>>(x08, nullptr, nullptr, nullptr, xa16, xa8, nullptr, offs, csr);
    k_layer<1><<<layer_blocks, 256, 0, stream>>>(xa8, nullptr, nullptr, nullptr, xb16, xb8, nullptr, offs, csr);
    k_layer<2><<<layer_blocks, 256, 0, stream>>>(xb8, emb, xa16, xb16, nullptr, nullptr, out, offs, csr);
}

// Round 26
// 97.295 us; speedup vs baseline: 1.0195x; 1.0195x over previous
//
#include <hip/hip_runtime.h>
#include <hip/hip_fp8.h>

#define NN 50000
#define DIM 64
#define NE 1250000
#define NPARTS 196  // ceil(50000/256)

// ---- counting-sort CSR build: 64 edge-slices x 8 row-ranges = 512 blocks
#define NSL 64
#define SLICEB 19532          // ceil(NE / NSL); 19532*64 = 1250048 >= NE
#define RANGE 6250            // NN / 8 rows per range
#define CSTRIDE 50048         // padded row stride of cnt matrix

typedef __attribute__((ext_vector_type(2))) float f32x2;

// bf16 helpers (RNE pack, cheap unpack)
__device__ __forceinline__ unsigned short f2b(float f) {
    unsigned int b = __builtin_bit_cast(unsigned int, f);
    b = (b + 0x7fffu + ((b >> 16) & 1u)) >> 16;
    return (unsigned short)b;
}
__device__ __forceinline__ float blo(unsigned int u) {
    return __builtin_bit_cast(float, u << 16);
}
__device__ __forceinline__ float bhi(unsigned int u) {
    return __builtin_bit_cast(float, u & 0xffff0000u);
}

// fp8 e4m3 (OCP) helpers — hardware cvt on gfx950; word-select must be constant.
template <bool HI>
__device__ __forceinline__ f32x2 dec2(unsigned int u) {
#if __has_builtin(__builtin_amdgcn_cvt_pk_f32_fp8)
    return __builtin_amdgcn_cvt_pk_f32_fp8(u, HI);
#else
    unsigned int b0 = HI ? ((u >> 16) & 0xff) : (u & 0xff);
    unsigned int b1 = HI ? ((u >> 24) & 0xff) : ((u >> 8) & 0xff);
    __hip_fp8_e4m3 t0, t1;
    t0.__x = (unsigned char)b0;
    t1.__x = (unsigned char)b1;
    f32x2 r;
    r[0] = (float)t0;
    r[1] = (float)t1;
    return r;
#endif
}
__device__ __forceinline__ unsigned int enc4(float v0, float v1, float v2, float v3) {
#if __has_builtin(__builtin_amdgcn_cvt_pk_fp8_f32)
    unsigned int r = 0;
    r = __builtin_amdgcn_cvt_pk_fp8_f32(v0, v1, r, false);
    r = __builtin_amdgcn_cvt_pk_fp8_f32(v2, v3, r, true);
    return r;
#else
    __hip_fp8_e4m3 t0(v0), t1(v1), t2(v2), t3(v3);
    return (unsigned int)t0.__x | ((unsigned int)t1.__x << 8) |
           ((unsigned int)t2.__x << 16) | ((unsigned int)t3.__x << 24);
#endif
}

// ---------------- hist + bucket staging + fp8 cvt side-job ----------------
// bid -> slice s = (bid&7)|((bid>>6)<<3), rng = (bid>>3)&7 (bid%8 == s%8:
// same-slice blocks co-scheduled on one XCD -> slice read into L2 once).
// Stages each in-range edge as packed (r-lo)<<16 | col into bucket
// (s*8+rng)*SLICEB via wave-aggregated ballot append (one LDS atomic/wave).
__global__ __launch_bounds__(1024) void k_hist(const int* __restrict__ row,
                                               const int* __restrict__ col,
                                               const float* __restrict__ emb,
                                               unsigned char* __restrict__ x08,
                                               unsigned short* __restrict__ cnt,
                                               unsigned int* __restrict__ stage,
                                               int* __restrict__ bsize) {
    __shared__ int h[RANGE];
    __shared__ int bcnt;
    int bid = blockIdx.x;
    int s   = (bid & 7) | ((bid >> 6) << 3);
    int rng = (bid >> 3) & 7;
    int lo = rng * RANGE;
    int tid = threadIdx.x;
    for (int i = tid; i < RANGE; i += 1024) h[i] = 0;
    if (tid == 0) bcnt = 0;
    __syncthreads();
    int beg = s * SLICEB;
    int end = beg + SLICEB;
    if (end > NE) end = NE;
    unsigned int* st = stage + (size_t)(s * 8 + rng) * SLICEB;
    int lane = tid & 63;
    for (int e = beg + tid; e < end; e += 1024) {
        int r = row[e] - lo;
        bool ok = (unsigned)r < RANGE;
        unsigned long long mask = __ballot(ok);
        if (ok) {
            int leader = __ffsll((long long)mask) - 1;
            int base = 0;
            if (lane == leader) base = atomicAdd(&bcnt, __popcll(mask));
            base = __shfl(base, leader);
            int off = __popcll(mask & ((1ull << lane) - 1ull));
            st[base + off] = ((unsigned int)r << 16) | (unsigned int)col[e];
            atomicAdd(&h[r], 1);  // LDS atomic
        }
    }
    __syncthreads();
    unsigned short* c = cnt + s * CSTRIDE + lo;
    for (int i = tid; i < RANGE; i += 1024) c[i] = (unsigned short)h[i];
    if (tid == 0) bsize[s * 8 + rng] = bcnt;
    // ----- independent side-job: fp32 emb -> fp8 mirror (1 iter/thread) -----
    for (int t = bid * 1024 + tid; t < NN * DIM / 8; t += 512 * 1024) {
        const float4* p = (const float4*)emb + t * 2;
        float4 a = p[0], b = p[1];
        uint2 pk;
        pk.x = enc4(a.x, a.y, a.z, a.w);
        pk.y = enc4(b.x, b.y, b.z, b.w);
        ((uint2*)x08)[t] = pk;
    }
}

// ---------------- rowscan + partial-sum fusion ----------------
__global__ __launch_bounds__(256) void k_rowscan(unsigned short* __restrict__ cnt,
                                                 int* __restrict__ deg,
                                                 int* __restrict__ partial) {
    __shared__ int sred[256];
    int t = threadIdx.x;
    int r = blockIdx.x * 256 + t;
    int acc = 0;
    if (r < NN) {
#pragma unroll
        for (int s = 0; s < NSL; ++s) {
            int c = cnt[s * CSTRIDE + r];
            cnt[s * CSTRIDE + r] = (unsigned short)acc;  // exclusive within-row offset
            acc += c;
        }
        deg[r] = acc;
    }
    sred[t] = acc;
    __syncthreads();
    for (int off = 128; off > 0; off >>= 1) {
        if (t < off) sred[t] += sred[t + off];
        __syncthreads();
    }
    if (t == 0) partial[blockIdx.x] = sred[0];
}

// ---------------- scan_final with inline top-scan ----------------
__global__ __launch_bounds__(256) void k_scan_final(const int* __restrict__ deg,
                                                    const int* __restrict__ partial,
                                                    int* __restrict__ offs) {
    __shared__ int ps[256];
    __shared__ int s[256];
    int t = threadIdx.x;
    ps[t] = (t < NPARTS) ? partial[t] : 0;
    __syncthreads();
    for (int off = 1; off < 256; off <<= 1) {
        int x = (t >= off) ? ps[t - off] : 0;
        __syncthreads();
        ps[t] += x;
        __syncthreads();
    }
    int bpre = (blockIdx.x == 0) ? 0 : ps[blockIdx.x - 1];
    int i = blockIdx.x * 256 + t;
    int v = (i < NN) ? deg[i] : 0;
    s[t] = v;
    __syncthreads();
    for (int off = 1; off < 256; off <<= 1) {
        int x = (t >= off) ? s[t - off] : 0;
        __syncthreads();
        s[t] += x;
        __syncthreads();
    }
    int excl = s[t] - v;
    if (i <= NN) offs[i] = bpre + excl;  // offs[NN] = NE (total)
}

// ---------------- CSR fill from staged buckets (NO global atomics) ----------------
__global__ __launch_bounds__(1024) void k_fillb(const unsigned int* __restrict__ stage,
                                                const int* __restrict__ bsize,
                                                const int* __restrict__ offs,
                                                const unsigned short* __restrict__ cnt,
                                                int* __restrict__ csr) {
    __shared__ int cur[RANGE];
    int bid = blockIdx.x;
    int s   = bid >> 3;
    int rng = bid & 7;
    int lo = rng * RANGE;
    int tid = threadIdx.x;
    const unsigned short* c = cnt + s * CSTRIDE + lo;
    const int* o = offs + lo;
    for (int i = tid; i < RANGE; i += 1024) cur[i] = o[i] + c[i];
    __syncthreads();
    int nb = bsize[s * 8 + rng];
    const unsigned int* st = stage + (size_t)(s * 8 + rng) * SLICEB;
    for (int i = tid; i < nb; i += 1024) {
        unsigned int pk = st[i];
        int r = pk >> 16;
        int pos = atomicAdd(&cur[r], 1);  // LDS atomic
        csr[pos] = (int)(pk & 0xffffu);
    }
}

// ---------------- one propagation layer (fp8 gather, fp32 accum) ----------------
// 8 nodes per wave: lane>>3 = node in wave, lane&7 = feature-octet.
// Gather source: fp8 mirror (3.2 MB, per-XCD-L2-resident, 64 B/edge).
// Measured best (r24: 97.0 us); r25's 16-node variant was null-to-negative,
// confirming the layers sit at the 1.25M-line-transaction/layer floor.
// bf16 copies kept ONLY for final out-assembly (fp8 error doesn't compound).
template <int PHASE>
__global__ __launch_bounds__(256) void k_layer(const unsigned char* __restrict__ xin8,
                                               const float* __restrict__ emb,
                                               const unsigned short* __restrict__ xa16,
                                               const unsigned short* __restrict__ xb16,
                                               unsigned short* __restrict__ xout16,
                                               unsigned char* __restrict__ xout8,
                                               float* __restrict__ out,
                                               const int* __restrict__ offs,
                                               const int* __restrict__ csr) {
    int wid = (blockIdx.x * blockDim.x + threadIdx.x) >> 6;
    int lane = threadIdx.x & 63;
    int sub = lane >> 3;    // node within wave (0..7)
    int sl = lane & 7;      // feature-octet index (0..7)
    int n = 8 * wid + sub;
    if (n >= NN) return;
    int beg = offs[n];
    int end = offs[n + 1];
    const unsigned char* xq = xin8 + sl * 8;  // + c*64 bytes per neighbor

    float a0 = 0.f, a1 = 0.f, a2 = 0.f, a3 = 0.f, a4 = 0.f, a5 = 0.f, a6 = 0.f, a7 = 0.f;
    float b0 = 0.f, b1 = 0.f, b2 = 0.f, b3 = 0.f, b4 = 0.f, b5 = 0.f, b6 = 0.f, b7 = 0.f;
    int e = beg;
    for (; e + 8 <= end; e += 8) {
        int c0 = csr[e + 0], c1 = csr[e + 1], c2 = csr[e + 2], c3 = csr[e + 3];
        int c4 = csr[e + 4], c5 = csr[e + 5], c6 = csr[e + 6], c7 = csr[e + 7];
        uint2 u0 = *(const uint2*)(xq + c0 * 64);
        uint2 u1 = *(const uint2*)(xq + c1 * 64);
        uint2 u2 = *(const uint2*)(xq + c2 * 64);
        uint2 u3 = *(const uint2*)(xq + c3 * 64);
        uint2 u4 = *(const uint2*)(xq + c4 * 64);
        uint2 u5 = *(const uint2*)(xq + c5 * 64);
        uint2 u6 = *(const uint2*)(xq + c6 * 64);
        uint2 u7 = *(const uint2*)(xq + c7 * 64);
        f32x2 p;
        p = dec2<false>(u0.x); a0 += p[0]; a1 += p[1];
        p = dec2<true >(u0.x); a2 += p[0]; a3 += p[1];
        p = dec2<false>(u0.y); a4 += p[0]; a5 += p[1];
        p = dec2<true >(u0.y); a6 += p[0]; a7 += p[1];
        p = dec2<false>(u1.x); b0 += p[0]; b1 += p[1];
        p = dec2<true >(u1.x); b2 += p[0]; b3 += p[1];
        p = dec2<false>(u1.y); b4 += p[0]; b5 += p[1];
        p = dec2<true >(u1.y); b6 += p[0]; b7 += p[1];
        p = dec2<false>(u2.x); a0 += p[0]; a1 += p[1];
        p = dec2<true >(u2.x); a2 += p[0]; a3 += p[1];
        p = dec2<false>(u2.y); a4 += p[0]; a5 += p[1];
        p = dec2<true >(u2.y); a6 += p[0]; a7 += p[1];
        p = dec2<false>(u3.x); b0 += p[0]; b1 += p[1];
        p = dec2<true >(u3.x); b2 += p[0]; b3 += p[1];
        p = dec2<false>(u3.y); b4 += p[0]; b5 += p[1];
        p = dec2<true >(u3.y); b6 += p[0]; b7 += p[1];
        p = dec2<false>(u4.x); a0 += p[0]; a1 += p[1];
        p = dec2<true >(u4.x); a2 += p[0]; a3 += p[1];
        p = dec2<false>(u4.y); a4 += p[0]; a5 += p[1];
        p = dec2<true >(u4.y); a6 += p[0]; a7 += p[1];
        p = dec2<false>(u5.x); b0 += p[0]; b1 += p[1];
        p = dec2<true >(u5.x); b2 += p[0]; b3 += p[1];
        p = dec2<false>(u5.y); b4 += p[0]; b5 += p[1];
        p = dec2<true >(u5.y); b6 += p[0]; b7 += p[1];
        p = dec2<false>(u6.x); a0 += p[0]; a1 += p[1];
        p = dec2<true >(u6.x); a2 += p[0]; a3 += p[1];
        p = dec2<false>(u6.y); a4 += p[0]; a5 += p[1];
        p = dec2<true >(u6.y); a6 += p[0]; a7 += p[1];
        p = dec2<false>(u7.x); b0 += p[0]; b1 += p[1];
        p = dec2<true >(u7.x); b2 += p[0]; b3 += p[1];
        p = dec2<false>(u7.y); b4 += p[0]; b5 += p[1];
        p = dec2<true >(u7.y); b6 += p[0]; b7 += p[1];
    }
    for (; e < end; ++e) {
        uint2 u = *(const uint2*)(xq + csr[e] * 64);
        f32x2 p;
        p = dec2<false>(u.x); a0 += p[0]; a1 += p[1];
        p = dec2<true >(u.x); a2 += p[0]; a3 += p[1];
        p = dec2<false>(u.y); a4 += p[0]; a5 += p[1];
        p = dec2<true >(u.y); a6 += p[0]; a7 += p[1];
    }

    int d = end - beg;
    float inv = (d > 0) ? 1.0f / (float)d : 0.0f;
    float v0 = (a0 + b0) * inv;
    float v1 = (a1 + b1) * inv;
    float v2 = (a2 + b2) * inv;
    float v3 = (a3 + b3) * inv;
    float v4 = (a4 + b4) * inv;
    float v5 = (a5 + b5) * inv;
    float v6 = (a6 + b6) * inv;
    float v7 = (a7 + b7) * inv;

    int o = n * DIM + sl * 8;
    if (PHASE < 2) {
        uint4 pk16 = {(unsigned int)f2b(v0) | ((unsigned int)f2b(v1) << 16),
                      (unsigned int)f2b(v2) | ((unsigned int)f2b(v3) << 16),
                      (unsigned int)f2b(v4) | ((unsigned int)f2b(v5) << 16),
                      (unsigned int)f2b(v6) | ((unsigned int)f2b(v7) << 16)};
        *(uint4*)(xout16 + o) = pk16;
        uint2 pk8;
        pk8.x = enc4(v0, v1, v2, v3);
        pk8.y = enc4(v4, v5, v6, v7);
        *(uint2*)(xout8 + o) = pk8;
    } else {
        float4 e0 = *(const float4*)(emb + o);
        float4 e1 = *(const float4*)(emb + o + 4);
        uint4 ua = *(const uint4*)(xa16 + o);
        uint4 ub = *(const uint4*)(xb16 + o);
        float4 o0, o1;
        o0.x = 0.25f * (e0.x + blo(ua.x) + blo(ub.x) + v0);
        o0.y = 0.25f * (e0.y + bhi(ua.x) + bhi(ub.x) + v1);
        o0.z = 0.25f * (e0.z + blo(ua.y) + blo(ub.y) + v2);
        o0.w = 0.25f * (e0.w + bhi(ua.y) + bhi(ub.y) + v3);
        o1.x = 0.25f * (e1.x + blo(ua.z) + blo(ub.z) + v4);
        o1.y = 0.25f * (e1.y + bhi(ua.z) + bhi(ub.z) + v5);
        o1.z = 0.25f * (e1.z + blo(ua.w) + blo(ub.w) + v6);
        o1.w = 0.25f * (e1.w + bhi(ua.w) + bhi(ub.w) + v7);
        *(float4*)(out + o) = o0;
        *(float4*)(out + o + 4) = o1;
    }
}

extern "C" void kernel_launch(void* const* d_in, const int* in_sizes, int n_in,
                              void* d_out, int out_size, void* d_ws, size_t ws_size,
                              hipStream_t stream) {
    const int* edge = (const int*)d_in[0];
    const int* row = edge;        // edge_index[0]
    const int* col = edge + NE;   // edge_index[1]
    const float* emb = (const float*)d_in[1];
    float* out = (float*)d_out;

    // workspace layout (~75 MB of 256 MB)
    int* deg    = (int*)d_ws;                                // 50048 ints
    int* offs   = deg + 50048;                               // 50112 ints
    int* partial= offs + 50112;                              // 256 ints
    int* bsize  = partial + 256;                             // 512 ints (pad 576)
    int* csr    = bsize + 576;                               // 1250048 ints
    unsigned short* cnt = (unsigned short*)(csr + 1250048);  // 64*50048 ushort (6.4MB)
    unsigned short* xa16 = cnt + (size_t)NSL * CSTRIDE;      // 3.2M ushort
    unsigned short* xb16 = xa16 + NN * DIM;                  // 3.2M ushort
    unsigned char* x08 = (unsigned char*)(xb16 + NN * DIM);  // 3.2M bytes
    unsigned char* xa8 = x08 + NN * DIM;                     // 3.2M bytes
    unsigned char* xb8 = xa8 + NN * DIM;                     // 3.2M bytes
    unsigned int* stage = (unsigned int*)(xb8 + NN * DIM);   // 512*19532 uints (40MB)

    k_hist      <<<NSL * 8, 1024, 0, stream>>>(row, col, emb, x08, cnt, stage, bsize);
    k_rowscan   <<<NPARTS, 256, 0, stream>>>(cnt, deg, partial);
    k_scan_final<<<NPARTS, 256, 0, stream>>>(deg, partial, offs);
    k_fillb     <<<NSL * 8, 1024, 0, stream>>>(stage, bsize, offs, cnt, csr);

    // 8 nodes per wave: 6250 waves -> 1563 blocks of 256 (guard in-kernel)
    int layer_blocks = 1563;
    k_layer<0><<<layer_blocks, 256, 0, stream>>>(x08, nullptr, nullptr, nullptr, xa16, xa8, nullptr, offs, csr);
    k_layer<1><<<layer_blocks, 256, 0, stream>>>(xa8, nullptr, nullptr, nullptr, xb16, xb8, nullptr, offs, csr);
    k_layer<2><<<layer_blocks, 256, 0, stream>>>(xb8, emb, xa16, xb16, nullptr, nullptr, out, offs, csr);
}